// Round 3
// baseline (38.626 us; speedup 1.0000x reference)
//
#include <hip/hip_runtime.h>

// x: [32,256,56,56] f32 (integer-valued), bc: [32] i32, weight/bias: [8,256] i32,
// z1/z2/z3/M0/shift: [8] i32. out: [32,256,56,56] f32.
//
// total = clip( rounding_rshift( multiply_M( ((xi-z1)*(w-z2)+bias) << left, M0 ),
//                                right ) + z3, -128, 127 )
//
// Pure streaming kernel (205.8 MB total traffic, zero reuse) -> nontemporal
// load/store (native clang vector type — HIP_vector_type is rejected by the
// nontemporal builtins).

#define HW_PLANE 3136   // 56*56
#define NFEAT    256

typedef float f32x4 __attribute__((ext_vector_type(4)));

__global__ __launch_bounds__(256) void qbn_kernel(
    const float* __restrict__ x,
    const int*   __restrict__ bc,
    const int*   __restrict__ weight,
    const int*   __restrict__ bias,
    const int*   __restrict__ z1,
    const int*   __restrict__ z2,
    const int*   __restrict__ z3,
    const int*   __restrict__ M0,
    const int*   __restrict__ shift,
    float*       __restrict__ out)
{
    const int plane = blockIdx.x;           // [0, B*C)
    const int b = plane >> 8;               // plane / 256
    const int c = plane & 255;              // plane % 256

    // Per-block (wave-uniform) parameters — scalar loads.
    const int cl  = bc[b];
    const int w   = weight[cl * NFEAT + c];
    const int bi  = bias[cl * NFEAT + c];
    const int zz1 = z1[cl];
    const int zz2 = z2[cl];
    const int zz3 = z3[cl];
    const int m0  = M0[cl];
    const int sh  = shift[cl];

    const int left  = sh < 0 ? -sh : 0;     // {0,1,2}
    const int right = sh > 0 ?  sh : 0;     // [0,8)
    const int wz    = w - zz2;
    const int lmul  = 1 << left;
    const int mask  = (1 << right) - 1;

    const f32x4* __restrict__ xin  = (const f32x4*)(x   + (size_t)plane * HW_PLANE);
    f32x4*       __restrict__ xout = (f32x4*)      (out + (size_t)plane * HW_PLANE);

    const int n4 = HW_PLANE / 4;            // 784
    for (int i = threadIdx.x; i < n4; i += 256) {
        f32x4 v = __builtin_nontemporal_load(&xin[i]);
        f32x4 o;
        #pragma unroll
        for (int k = 0; k < 4; ++k) {
            int xi  = (int)v[k];                         // exact: x holds 0..255
            int sub = (xi - zz1) * wz + bi;              // int32-safe (<2^19)
            long long prod  = (long long)(sub * lmul) * (long long)m0;
            long long nudge = (prod >= 0) ? (1LL << 30) : (1LL - (1LL << 30));
            int t   = (int)((prod + nudge) >> 31);       // |t| < 2^21
            int rem = t & mask;
            int thr = (mask >> 1) + (t < 0 ? 1 : 0);
            int res = (t >> right) + ((rem > thr) ? 1 : 0) + zz3;
            res = res < -128 ? -128 : (res > 127 ? 127 : res);
            o[k] = (float)res;
        }
        __builtin_nontemporal_store(o, &xout[i]);
    }
}

extern "C" void kernel_launch(void* const* d_in, const int* in_sizes, int n_in,
                              void* d_out, int out_size, void* d_ws, size_t ws_size,
                              hipStream_t stream) {
    const float* x      = (const float*)d_in[0];
    const int*   bc     = (const int*)  d_in[1];
    const int*   weight = (const int*)  d_in[2];
    const int*   bias   = (const int*)  d_in[3];
    const int*   z1     = (const int*)  d_in[4];
    const int*   z2     = (const int*)  d_in[5];
    const int*   z3     = (const int*)  d_in[6];
    const int*   M0     = (const int*)  d_in[7];
    const int*   shift  = (const int*)  d_in[8];
    float*       out    = (float*)d_out;

    const int B = in_sizes[1];              // 32
    const int planes = B * NFEAT;           // 8192
    qbn_kernel<<<planes, 256, 0, stream>>>(x, bc, weight, bias, z1, z2, z3, M0, shift, out);
}

// Round 4
// 36.335 us; speedup vs baseline: 1.0630x; 1.0630x over previous
//
#include <hip/hip_runtime.h>

// x: [32,256,56,56] f32 (integer-valued), bc: [32] i32, weight/bias: [8,256] i32,
// z1/z2/z3/M0/shift: [8] i32. out: [32,256,56,56] f32.
//
// total = clip( rounding_rshift( multiply_M( ((xi-z1)*(w-z2)+bias) << left, M0 ),
//                                right ) + z3, -128, 127 )
//
// Pure streaming kernel (205.8 MB total traffic, zero reuse).
// R2 lesson: nt on LOADS regressed 6% — keep loads plain, nt on stores only.

#define HW_PLANE 3136   // 56*56
#define NFEAT    256

typedef float f32x4 __attribute__((ext_vector_type(4)));

__global__ __launch_bounds__(256) void qbn_kernel(
    const float* __restrict__ x,
    const int*   __restrict__ bc,
    const int*   __restrict__ weight,
    const int*   __restrict__ bias,
    const int*   __restrict__ z1,
    const int*   __restrict__ z2,
    const int*   __restrict__ z3,
    const int*   __restrict__ M0,
    const int*   __restrict__ shift,
    float*       __restrict__ out)
{
    const int plane = blockIdx.x;           // [0, B*C)
    const int b = plane >> 8;               // plane / 256
    const int c = plane & 255;              // plane % 256

    // Per-block (wave-uniform) parameters — scalar loads.
    const int cl  = bc[b];
    const int w   = weight[cl * NFEAT + c];
    const int bi  = bias[cl * NFEAT + c];
    const int zz1 = z1[cl];
    const int zz2 = z2[cl];
    const int zz3 = z3[cl];
    const int m0  = M0[cl];
    const int sh  = shift[cl];

    const int left  = sh < 0 ? -sh : 0;     // {0,1,2}
    const int right = sh > 0 ?  sh : 0;     // [0,8)
    const int wz    = w - zz2;
    const int lmul  = 1 << left;
    const int mask  = (1 << right) - 1;

    const f32x4* __restrict__ xin  = (const f32x4*)(x   + (size_t)plane * HW_PLANE);
    f32x4*       __restrict__ xout = (f32x4*)      (out + (size_t)plane * HW_PLANE);

    const int n4 = HW_PLANE / 4;            // 784
    for (int i = threadIdx.x; i < n4; i += 256) {
        f32x4 v = xin[i];                                // plain load (nt load hurt)
        f32x4 o;
        #pragma unroll
        for (int k = 0; k < 4; ++k) {
            int xi  = (int)v[k];                         // exact: x holds 0..255
            int sub = (xi - zz1) * wz + bi;              // int32-safe (<2^19)
            long long prod  = (long long)(sub * lmul) * (long long)m0;
            long long nudge = (prod >= 0) ? (1LL << 30) : (1LL - (1LL << 30));
            int t   = (int)((prod + nudge) >> 31);       // |t| < 2^21
            int rem = t & mask;
            int thr = (mask >> 1) + (t < 0 ? 1 : 0);
            int res = (t >> right) + ((rem > thr) ? 1 : 0) + zz3;
            res = res < -128 ? -128 : (res > 127 ? 127 : res);
            o[k] = (float)res;
        }
        __builtin_nontemporal_store(o, &xout[i]);        // nt store: no L2 residency needed
    }
}

extern "C" void kernel_launch(void* const* d_in, const int* in_sizes, int n_in,
                              void* d_out, int out_size, void* d_ws, size_t ws_size,
                              hipStream_t stream) {
    const float* x      = (const float*)d_in[0];
    const int*   bc     = (const int*)  d_in[1];
    const int*   weight = (const int*)  d_in[2];
    const int*   bias   = (const int*)  d_in[3];
    const int*   z1     = (const int*)  d_in[4];
    const int*   z2     = (const int*)  d_in[5];
    const int*   z3     = (const int*)  d_in[6];
    const int*   M0     = (const int*)  d_in[7];
    const int*   shift  = (const int*)  d_in[8];
    float*       out    = (float*)d_out;

    const int B = in_sizes[1];              // 32
    const int planes = B * NFEAT;           // 8192
    qbn_kernel<<<planes, 256, 0, stream>>>(x, bc, weight, bias, z1, z2, z3, M0, shift, out);
}